// Round 17
// baseline (468.866 us; speedup 1.0000x reference)
//
#include <hip/hip_runtime.h>
#include <hip/hip_bf16.h>
#include <cmath>

#define HEADS 4
typedef __hip_bfloat16 bf16;
typedef short short8 __attribute__((ext_vector_type(8)));
typedef unsigned short us8 __attribute__((ext_vector_type(8)));
typedef float floatx4 __attribute__((ext_vector_type(4)));
typedef float floatx2 __attribute__((ext_vector_type(2)));
typedef unsigned int u32;

__device__ inline float bf2f(unsigned short u) {
    union { unsigned u; float f; } c; c.u = ((unsigned)u) << 16; return c.f;
}
__device__ inline short f2bs(float f) {
    bf16 h = __float2bfloat16(f);
    return *reinterpret_cast<short*>(&h);
}
__device__ __forceinline__ unsigned pack_bf16(float a, float b) {
    return (((unsigned)(unsigned short)f2bs(b)) << 16) | (unsigned short)f2bs(a);
}
// pack 4 floats -> 4 fp8 e4m3 bytes (OCP, gfx950 HW cvt)
__device__ __forceinline__ unsigned pack_fp8x4(float a, float b, float c, float d) {
    unsigned lo = __builtin_amdgcn_cvt_pk_fp8_f32(a, b, 0, false);
    return __builtin_amdgcn_cvt_pk_fp8_f32(c, d, lo, true);
}

// async 16B global->LDS (DMA, no VGPR round-trip). LDS dest: wave-uniform base + lane*16.
__device__ __forceinline__ void ld_lds16(const void* g, void* l) {
    __builtin_amdgcn_global_load_lds((const __attribute__((address_space(1))) u32*)g,
                                     (__attribute__((address_space(3))) u32*)l, 16, 0, 0);
}

// ---- problem constants ----
__device__ const int g_ND[3]   = {50000, 10000, 2048};
__device__ const int g_OOFF[3] = {0, 50001, 60002};
__device__ const int g_NE[3]   = {800000, 400000, 100000};
__device__ const int g_SOFF[3] = {0, 800000, 1200000};
// coarse bucket width per layer: 256 buckets cover nd (256*S >= nd)
__device__ const int g_S[3]    = {196, 40, 8};

#define NBIN 256   // coarse dst-buckets per layer (r17: finer -> smaller expand LDS)
#define NBLK 128   // edge-chunk blocks per layer for the partition pass
#define MAXB 4096  // max edges per bucket handled via LDS (avg 3125 for layer 0)
#define MAXS 196   // max fine dsts per bucket
#define PF 4

// ------- weights transpose-cast (5 slabs) + per-layer coarse histograms, one dispatch -------
__global__ void precast_all(const float* __restrict__ W0, const float* __restrict__ W1,
                            const float* __restrict__ W2, const float* __restrict__ W3,
                            const float* __restrict__ W4,
                            bf16* __restrict__ B0, bf16* __restrict__ B1, bf16* __restrict__ B2,
                            bf16* __restrict__ B3, bf16* __restrict__ B4,
                            const int* __restrict__ d0, const int* __restrict__ d1,
                            const int* __restrict__ d2, int* __restrict__ blockhist)
{
    int y = blockIdx.y;
    if (y >= 5) {
        int l = y - 5;
        const int* dst = (l == 0) ? d0 : (l == 1) ? d1 : d2;
        int ne = g_NE[l], S = g_S[l];
        __shared__ int h[NBIN];
        for (int i = threadIdx.x; i < NBIN; i += blockDim.x) h[i] = 0;
        __syncthreads();
        int per = (ne + NBLK - 1) / NBLK;
        int st = blockIdx.x * per;
        int en = min(st + per, ne);
        for (int i = st + threadIdx.x; i < en; i += blockDim.x)
            atomicAdd(&h[dst[i] / S], 1);
        __syncthreads();
        for (int i = threadIdx.x; i < NBIN; i += blockDim.x)
            blockhist[(l * NBIN + i) * NBLK + blockIdx.x] = h[i];
        return;
    }
    const int Ks[5] = {128, 256, 256, 128, 256};
    const int Ns[5] = {256, 256, 188, 256, 256};
    const float* W = (y == 0) ? W0 : (y == 1) ? W1 : (y == 2) ? W2 : (y == 3) ? W3 : W4;
    bf16* B = (y == 0) ? B0 : (y == 1) ? B1 : (y == 2) ? B2 : (y == 3) ? B3 : B4;
    int K = Ks[y], N = Ns[y], sz = K * N;
    for (int i = blockIdx.x * blockDim.x + threadIdx.x; i < sz; i += gridDim.x * blockDim.x) {
        int n = i / K, k = i % K;
        B[i] = __float2bfloat16(W[(size_t)k * N + n]);
    }
}

// -------- MFMA GEMM: C[M,N] = A[M,K] @ Bt[N,K]^T, BN=256 BK=64 (shape-templated) -----
// BIG=1: 512 thr, BM=128 (8 waves, 2Mx4N) -- best for large grids (L0).
// BIG=0: 256 thr, BM=64  (4 waves, 1Mx4N) -- best for small grids (L1/L2, more blocks).
// Swapped-operand MFMA: acc[mt][nt][e] = C[row0+wm+mt*16+r][wn+nt*16+q*4+e].
// AF32: A f32, cast fused into staging. SKIP: fused skip half-pass. EL2: D=47 el/er.
template<int BIG, int FUSE, int EL, int OUT8, int AF32, int SKIP, int EL2>
__global__ __launch_bounds__(BIG ? 512 : 256)
void gemm_mfma(const void* __restrict__ Ain, const bf16* __restrict__ Bt,
               const bf16* __restrict__ add, const float* __restrict__ bias,
               const float* __restrict__ al, const float* __restrict__ ar,
               float* __restrict__ el, float* __restrict__ er,
               void* __restrict__ Cb, int M, int N, int K, int nd,
               const bf16* __restrict__ Bt2, bf16* __restrict__ Cb2)
{
    const int BK = 64;
    const int THREADS = BIG ? 512 : 256;
    const int BM = BIG ? 128 : 64;
    const int SR = THREADS / 8;          // staging rows per ld_lds16 call
    const int NBC = 256 / SR;            // B staging calls
    __shared__ short As[BM * BK];        // 16 KB / 8 KB (EL2 reuses as float)
    __shared__ short Bs[256 * BK];       // 32 KB
    int tid = threadIdx.x;
    int wave = tid >> 6, lane = tid & 63;
    int q = lane >> 4, r = lane & 15;
    int row0 = blockIdx.y * BM;
    int wm = BIG ? ((wave >> 2) * 64) : 0;
    int wn = (wave & 3) * 64;

    const short* B16 = (const short*)Bt;
    int srow = tid >> 3;                       // 0..SR-1 rows per staging call
    int scol = ((tid & 7) ^ (srow & 7)) * 8;   // inverse-swizzled source granule
    const short* ga0s = nullptr; const short* ga1s = nullptr;
    const float* gaf0s = nullptr; const float* gaf1s = nullptr;
    if (AF32) {
        int arow0 = min(row0 + srow, M - 1);
        int arow1 = min(row0 + SR + srow, M - 1);
        gaf0s = (const float*)Ain + (size_t)arow0 * K + scol;
        gaf1s = (const float*)Ain + (size_t)arow1 * K + scol;
    } else {
        const short* A16 = (const short*)Ain;
        ga0s = A16 + (size_t)(row0 + srow) * K + scol;
        ga1s = ga0s + (size_t)SR * K;
    }
    char* la = (char*)As + tid * 16;
    char* lb = (char*)Bs + tid * 16;

    floatx4 zero = {0.f, 0.f, 0.f, 0.f};
    floatx4 acc[4][4];
#pragma unroll
    for (int i = 0; i < 4; i++)
#pragma unroll
        for (int j = 0; j < 4; j++) acc[i][j] = zero;

    {
        const short* gb = B16 + (size_t)srow * K + scol;
        const short* ga0 = ga0s; const short* ga1 = ga1s;
        const float* gaf0 = gaf0s; const float* gaf1 = gaf1s;
        for (int k0 = 0; k0 < K; k0 += BK) {
#pragma unroll
            for (int j = 0; j < NBC; j++)
                ld_lds16(gb + (size_t)(j * SR) * K, lb + j * THREADS * 16);
            gb += BK;
            if (AF32) {
                float4 a0 = *(const float4*)gaf0;
                float4 a1 = *(const float4*)(gaf0 + 4);
                float4 b0 = *(const float4*)gaf1;
                float4 b1 = *(const float4*)(gaf1 + 4);
                uint4 w0 = {pack_bf16(a0.x, a0.y), pack_bf16(a0.z, a0.w),
                            pack_bf16(a1.x, a1.y), pack_bf16(a1.z, a1.w)};
                uint4 w1 = {pack_bf16(b0.x, b0.y), pack_bf16(b0.z, b0.w),
                            pack_bf16(b1.x, b1.y), pack_bf16(b1.z, b1.w)};
                *(uint4*)la = w0;
                *(uint4*)(la + THREADS * 16) = w1;
                gaf0 += BK; gaf1 += BK;
            } else {
                ld_lds16(ga0, la);
                ld_lds16(ga1, la + THREADS * 16);
                ga0 += BK; ga1 += BK;
            }
            __syncthreads();
#pragma unroll
            for (int ks = 0; ks < 2; ks++) {
                int gr = (((ks << 2) | q) ^ (r & 7)) * 8;
                short8 af[4], bfr[4];
#pragma unroll
                for (int mt = 0; mt < 4; mt++)
                    af[mt] = *(short8*)&As[(wm + mt * 16 + r) * BK + gr];
#pragma unroll
                for (int nt = 0; nt < 4; nt++)
                    bfr[nt] = *(short8*)&Bs[(wn + nt * 16 + r) * BK + gr];
#pragma unroll
                for (int mt = 0; mt < 4; mt++)
#pragma unroll
                    for (int nt = 0; nt < 4; nt++)
                        acc[mt][nt] = __builtin_amdgcn_mfma_f32_16x16x32_bf16(bfr[nt], af[mt], acc[mt][nt], 0, 0, 0);
            }
            __syncthreads();
        }
    }

    // epilogue: per (mt,nt) lane holds C[grow][n0..n0+3], grow = row0+wm+mt*16+r
#pragma unroll
    for (int mt = 0; mt < 4; mt++) {
        int grow = row0 + wm + mt * 16 + r;
        if (grow >= M) continue;
#pragma unroll
        for (int nt = 0; nt < 4; nt++) {
            int n0 = wn + nt * 16 + q * 4;
            floatx4 v = acc[mt][nt];
            if (FUSE == 1) {
                ushort4 ad = *(const ushort4*)&add[(size_t)grow * N + n0];
                float4 bi = *(const float4*)&bias[n0];
                v[0] += bf2f(ad.x) + bi.x;
                v[1] += bf2f(ad.y) + bi.y;
                v[2] += bf2f(ad.z) + bi.z;
                v[3] += bf2f(ad.w) + bi.w;
#pragma unroll
                for (int e = 0; e < 4; e++) v[e] = (v[e] > 0.f) ? v[e] : (__expf(v[e]) - 1.f);
            }
            if (OUT8) {
                *(u32*)((unsigned char*)Cb + (size_t)grow * N + n0) =
                    pack_fp8x4(v[0], v[1], v[2], v[3]);
            } else if (n0 + 3 < N) {      // bounds-guard packed store (N=188 layer 2)
                uint2 o = {pack_bf16(v[0], v[1]), pack_bf16(v[2], v[3])};
                *(uint2*)((unsigned short*)Cb + (size_t)grow * N + n0) = o;
            } else {
#pragma unroll
                for (int e = 0; e < 4; e++)
                    if (n0 + e < N)
                        ((unsigned short*)Cb)[(size_t)grow * N + n0 + e] = (unsigned short)f2bs(v[e]);
            }
        }
    }

    if (EL) {
        int head = wave & 3;   // wn == head*64
#pragma unroll
        for (int mt = 0; mt < 4; mt++) {
            float pl = 0.f, pr = 0.f;
#pragma unroll
            for (int nt = 0; nt < 4; nt++) {
                int nn = nt * 16 + q * 4;
                float4 av = *(const float4*)&al[head * 64 + nn];
                float4 rv = *(const float4*)&ar[head * 64 + nn];
                floatx4 v = acc[mt][nt];
                pl += v[0] * av.x + v[1] * av.y + v[2] * av.z + v[3] * av.w;
                pr += v[0] * rv.x + v[1] * rv.y + v[2] * rv.z + v[3] * rv.w;
            }
            pl += __shfl_xor(pl, 16); pl += __shfl_xor(pl, 32);
            pr += __shfl_xor(pr, 16); pr += __shfl_xor(pr, 32);
            int grow = row0 + wm + mt * 16 + r;
            if (lane < 16 && grow < M) {
                el[grow * 4 + head] = pl;
                if (grow < nd) er[grow * 4 + head] = pr;
            }
        }
    }

    // ---- EL2: D=47 el/er fused epilogue (layer 2). al/ar flat [188]. ----
    if (EL2) {
        float* part = (float*)As;   // [row 0..BM-1][wnidx 0..3][h 0..3][2] = BM*32 f32
        int wnidx = wave & 3;
#pragma unroll
        for (int mt = 0; mt < 4; mt++) {
            float pl[4] = {0.f, 0.f, 0.f, 0.f};
            float pr[4] = {0.f, 0.f, 0.f, 0.f};
#pragma unroll
            for (int nt = 0; nt < 4; nt++) {
                int n0 = wn + nt * 16 + q * 4;
                floatx4 v = acc[mt][nt];
#pragma unroll
                for (int e = 0; e < 4; e++) {
                    int c = n0 + e;
                    if (c < 188) {
                        int h = (c >= 141) ? 3 : (c >= 94) ? 2 : (c >= 47) ? 1 : 0;
                        pl[h] += v[e] * al[c];
                        pr[h] += v[e] * ar[c];
                    }
                }
            }
#pragma unroll
            for (int h = 0; h < 4; h++) {
                pl[h] += __shfl_xor(pl[h], 16); pl[h] += __shfl_xor(pl[h], 32);
                pr[h] += __shfl_xor(pr[h], 16); pr[h] += __shfl_xor(pr[h], 32);
            }
            if (lane < 16) {
                int row = wm + mt * 16 + r;
#pragma unroll
                for (int h = 0; h < 4; h++) {
                    part[row * 32 + wnidx * 8 + h * 2 + 0] = pl[h];
                    part[row * 32 + wnidx * 8 + h * 2 + 1] = pr[h];
                }
            }
        }
        __syncthreads();
        int row = tid >> 2, h = tid & 3;   // THREADS = BM rows x 4 heads
        int grow = row0 + row;
        if (grow < M) {
            float ev = part[row * 32 + 0 + h * 2]     + part[row * 32 + 8 + h * 2]
                     + part[row * 32 + 16 + h * 2]    + part[row * 32 + 24 + h * 2];
            float rv = part[row * 32 + 0 + h * 2 + 1] + part[row * 32 + 8 + h * 2 + 1]
                     + part[row * 32 + 16 + h * 2 + 1]+ part[row * 32 + 24 + h * 2 + 1];
            el[grow * 4 + h] = ev;
            if (grow < nd) er[grow * 4 + h] = rv;
        }
    }

    // ---- skip half-pass: xs = A @ Bt2^T (bf16), rows < nd only ----
    if (SKIP) {
        if (row0 >= nd) return;
#pragma unroll
        for (int i = 0; i < 4; i++)
#pragma unroll
            for (int j = 0; j < 4; j++) acc[i][j] = zero;
        const short* gb2 = (const short*)Bt2 + (size_t)srow * K + scol;
        const short* ga0 = ga0s; const short* ga1 = ga1s;
        const float* gaf0 = gaf0s; const float* gaf1 = gaf1s;
        for (int k0 = 0; k0 < K; k0 += BK) {
#pragma unroll
            for (int j = 0; j < NBC; j++)
                ld_lds16(gb2 + (size_t)(j * SR) * K, lb + j * THREADS * 16);
            gb2 += BK;
            if (AF32) {
                float4 a0 = *(const float4*)gaf0;
                float4 a1 = *(const float4*)(gaf0 + 4);
                float4 b0 = *(const float4*)gaf1;
                float4 b1 = *(const float4*)(gaf1 + 4);
                uint4 w0 = {pack_bf16(a0.x, a0.y), pack_bf16(a0.z, a0.w),
                            pack_bf16(a1.x, a1.y), pack_bf16(a1.z, a1.w)};
                uint4 w1 = {pack_bf16(b0.x, b0.y), pack_bf16(b0.z, b0.w),
                            pack_bf16(b1.x, b1.y), pack_bf16(b1.z, b1.w)};
                *(uint4*)la = w0;
                *(uint4*)(la + THREADS * 16) = w1;
                gaf0 += BK; gaf1 += BK;
            } else {
                ld_lds16(ga0, la);
                ld_lds16(ga1, la + THREADS * 16);
                ga0 += BK; ga1 += BK;
            }
            __syncthreads();
#pragma unroll
            for (int ks = 0; ks < 2; ks++) {
                int gr = (((ks << 2) | q) ^ (r & 7)) * 8;
                short8 af[4], bfr[4];
#pragma unroll
                for (int mt = 0; mt < 4; mt++)
                    af[mt] = *(short8*)&As[(wm + mt * 16 + r) * BK + gr];
#pragma unroll
                for (int nt = 0; nt < 4; nt++)
                    bfr[nt] = *(short8*)&Bs[(wn + nt * 16 + r) * BK + gr];
#pragma unroll
                for (int mt = 0; mt < 4; mt++)
#pragma unroll
                    for (int nt = 0; nt < 4; nt++)
                        acc[mt][nt] = __builtin_amdgcn_mfma_f32_16x16x32_bf16(bfr[nt], af[mt], acc[mt][nt], 0, 0, 0);
            }
            __syncthreads();
        }
#pragma unroll
        for (int mt = 0; mt < 4; mt++) {
            int grow = row0 + wm + mt * 16 + r;
            if (grow >= nd) continue;
#pragma unroll
            for (int nt = 0; nt < 4; nt++) {
                int n0 = wn + nt * 16 + q * 4;
                floatx4 v = acc[mt][nt];
                uint2 o = {pack_bf16(v[0], v[1]), pack_bf16(v[2], v[3])};
                *(uint2*)((unsigned short*)Cb2 + (size_t)grow * 256 + n0) = o;
            }
        }
    }
}

// ---- fused coarse_scan + bin_scan (r17): 3 blocks x 256 threads ----
// Phase 1: bucket totals -> inclusive scan -> bbase (exclusive). Phase 2: thread t
// serially scans bucket t's 128 per-block counts -> binbase.
__global__ __launch_bounds__(NBIN)
void scans_fused(const int* __restrict__ blockhist, int* __restrict__ bbase,
                 int* __restrict__ offs, int* __restrict__ binbase)
{
    int l = blockIdx.x;
    int t = threadIdx.x;   // 0..NBIN-1
    __shared__ int s[NBIN];
    int tot = 0;
    for (int k = 0; k < NBLK; k++) tot += blockhist[(l * NBIN + t) * NBLK + k];
    s[t] = tot;
    __syncthreads();
    for (int off = 1; off < NBIN; off <<= 1) {
        int a = (t >= off) ? s[t - off] : 0;
        __syncthreads();
        s[t] += a;
        __syncthreads();
    }
    bbase[l * (NBIN + 1) + t + 1] = s[t];
    if (t == 0) {
        bbase[l * (NBIN + 1)] = 0;
        offs[g_OOFF[l] + g_ND[l]] = g_NE[l];
    }
    __syncthreads();
    int run = (t == 0) ? 0 : s[t - 1];   // exclusive bucket base
    for (int k = 0; k < NBLK; k++) {
        binbase[(l * NBIN + t) * NBLK + k] = run;
        run += blockhist[(l * NBIN + t) * NBLK + k];
    }
}

__global__ __launch_bounds__(256)
void bin_scatter(const int* __restrict__ s0, const int* __restrict__ d0,
                 const int* __restrict__ s1, const int* __restrict__ d1,
                 const int* __restrict__ s2, const int* __restrict__ d2,
                 const int* __restrict__ base, int* __restrict__ stage)
{
    int l = blockIdx.y;
    const int* src = (l == 0) ? s0 : (l == 1) ? s1 : s2;
    const int* dst = (l == 0) ? d0 : (l == 1) ? d1 : d2;
    int ne = g_NE[l], S = g_S[l], soff = g_SOFF[l];
    __shared__ int cur[NBIN];
    for (int i = threadIdx.x; i < NBIN; i += blockDim.x)
        cur[i] = base[(l * NBIN + i) * NBLK + blockIdx.x];
    __syncthreads();
    int per = (ne + NBLK - 1) / NBLK;
    int st = blockIdx.x * per;
    int en = min(st + per, ne);
    for (int i = st + threadIdx.x; i < en; i += blockDim.x) {
        int dv = dst[i];
        int b = dv / S;
        int ldst = dv - b * S;
        int p = atomicAdd(&cur[b], 1);
        stage[soff + p] = src[i] | (ldst << 18);
    }
}

__global__ __launch_bounds__(256)
void bin_expand(const int* __restrict__ stage, const int* __restrict__ bbase,
                int* __restrict__ offs, int* __restrict__ ssrc)
{
    int l = blockIdx.y, b = blockIdx.x;
    int S = g_S[l], nd = g_ND[l], ooff = g_OOFF[l], soff = g_SOFF[l];
    int dlo = b * S;
    if (dlo >= nd) return;
    int dhi = min(dlo + S, nd);
    int base = bbase[l * (NBIN + 1) + b];
    int end  = bbase[l * (NBIN + 1) + b + 1];
    int cnt  = end - base;
    int tid = threadIdx.x;
    __shared__ int sdata[MAXB];
    __shared__ int outb[MAXB];
    __shared__ int lh[512];
    __shared__ int lcur[MAXS];
    lh[tid] = 0; lh[tid + 256] = 0;
    __syncthreads();
    if (cnt <= MAXB) {
        for (int i = tid; i < cnt; i += 256) {
            int v = stage[soff + base + i];
            sdata[i] = v;
            atomicAdd(&lh[v >> 18], 1);
        }
        __syncthreads();
        for (int off = 1; off < 512; off <<= 1) {
            int a0 = (tid >= off) ? lh[tid - off] : 0;
            int a1 = lh[tid + 256 - off];
            __syncthreads();
            lh[tid] += a0; lh[tid + 256] += a1;
            __syncthreads();
        }
        for (int d = tid; d < dhi - dlo; d += 256) {
            int ex = (d == 0) ? 0 : lh[d - 1];
            offs[ooff + dlo + d] = base + ex;
            lcur[d] = ex;
        }
        __syncthreads();
        for (int i = tid; i < cnt; i += 256) {
            int v = sdata[i];
            int p = atomicAdd(&lcur[v >> 18], 1);
            outb[p] = v & 0x3FFFF;
        }
        __syncthreads();
        for (int i = tid; i < cnt; i += 256)
            ssrc[soff + base + i] = outb[i];
    } else {
        for (int i = tid; i < cnt; i += 256)
            atomicAdd(&lh[stage[soff + base + i] >> 18], 1);
        __syncthreads();
        for (int off = 1; off < 512; off <<= 1) {
            int a0 = (tid >= off) ? lh[tid - off] : 0;
            int a1 = lh[tid + 256 - off];
            __syncthreads();
            lh[tid] += a0; lh[tid + 256] += a1;
            __syncthreads();
        }
        for (int d = tid; d < dhi - dlo; d += 256) {
            int ex = (d == 0) ? 0 : lh[d - 1];
            offs[ooff + dlo + d] = base + ex;
            lcur[d] = ex;
        }
        __syncthreads();
        for (int i = tid; i < cnt; i += 256) {
            int v = stage[soff + base + i];
            int p = atomicAdd(&lcur[v >> 18], 1);
            ssrc[soff + base + p] = v & 0x3FFFF;
        }
    }
}

// ---------------- fused attention+aggregation, D=64 (HD=256), fp8 fs rows ----------------
template<int FUSEH>
__global__ __launch_bounds__(256)
void attn_agg64(const unsigned char* __restrict__ fs8, const float* __restrict__ el,
                const float* __restrict__ er, const float* __restrict__ b,
                const int* __restrict__ offs, const int* __restrict__ ssrc,
                const bf16* __restrict__ xs, const float* __restrict__ bs2,
                bf16* __restrict__ rst, int nd)
{
    int wave = threadIdx.x >> 6, lane = threadIdx.x & 63;
    int n = blockIdx.x * 4 + wave;
    if (n >= nd) return;
    int s0 = offs[n], s1 = offs[n + 1];
    float4 erv = *(const float4*)&er[(size_t)n * 4];
    int half = lane >> 5, sub = lane & 31, head = sub >> 3;
    float eh = (head == 0) ? erv.x : (head == 1) ? erv.y : (head == 2) ? erv.z : erv.w;

    floatx2 acc[4];
#pragma unroll
    for (int j = 0; j < 4; j++) acc[j] = (floatx2){0.f, 0.f};
    float s = 0.f;

    int cnt = s1 - s0;
    int npairs = cnt >> 1;
    int i = s0 + half;
    if (npairs > 0) {
        int sid = ssrc[i];
        float ev = el[(size_t)sid * 4 + head];
        uint2 f = *(const uint2*)&fs8[(size_t)sid * 256 + sub * 8];
        for (int p = 1; p < npairs; p++) {
            i += 2;
            int sid2 = ssrc[i];
            float ev2 = el[(size_t)sid2 * 4 + head];
            uint2 f2 = *(const uint2*)&fs8[(size_t)sid2 * 256 + sub * 8];
            float e = ev + eh; e = (e > 0.f) ? e : 0.2f * e;
            float a = __expf(fminf(e, 60.f));
            s += a;
            floatx2 aa = {a, a};
            acc[0] = __builtin_elementwise_fma((floatx2)__builtin_amdgcn_cvt_pk_f32_fp8(f.x, false), aa, acc[0]);
            acc[1] = __builtin_elementwise_fma((floatx2)__builtin_amdgcn_cvt_pk_f32_fp8(f.x, true),  aa, acc[1]);
            acc[2] = __builtin_elementwise_fma((floatx2)__builtin_amdgcn_cvt_pk_f32_fp8(f.y, false), aa, acc[2]);
            acc[3] = __builtin_elementwise_fma((floatx2)__builtin_amdgcn_cvt_pk_f32_fp8(f.y, true),  aa, acc[3]);
            ev = ev2; f = f2;
        }
        float e = ev + eh; e = (e > 0.f) ? e : 0.2f * e;
        float a = __expf(fminf(e, 60.f));
        s += a;
        floatx2 aa = {a, a};
        acc[0] = __builtin_elementwise_fma((floatx2)__builtin_amdgcn_cvt_pk_f32_fp8(f.x, false), aa, acc[0]);
        acc[1] = __builtin_elementwise_fma((floatx2)__builtin_amdgcn_cvt_pk_f32_fp8(f.x, true),  aa, acc[1]);
        acc[2] = __builtin_elementwise_fma((floatx2)__builtin_amdgcn_cvt_pk_f32_fp8(f.y, false), aa, acc[2]);
        acc[3] = __builtin_elementwise_fma((floatx2)__builtin_amdgcn_cvt_pk_f32_fp8(f.y, true),  aa, acc[3]);
    }
    if (cnt & 1) {
        int idx = s1 - 1;
        int sid = ssrc[idx];
        float ev = el[(size_t)sid * 4 + head];
        uint2 f = *(const uint2*)&fs8[(size_t)sid * 256 + sub * 8];
        float e = ev + eh; e = (e > 0.f) ? e : 0.2f * e;
        float a = __expf(fminf(e, 60.f));
        if (half) a = 0.f;
        s += a;
        floatx2 aa = {a, a};
        acc[0] = __builtin_elementwise_fma((floatx2)__builtin_amdgcn_cvt_pk_f32_fp8(f.x, false), aa, acc[0]);
        acc[1] = __builtin_elementwise_fma((floatx2)__builtin_amdgcn_cvt_pk_f32_fp8(f.x, true),  aa, acc[1]);
        acc[2] = __builtin_elementwise_fma((floatx2)__builtin_amdgcn_cvt_pk_f32_fp8(f.y, false), aa, acc[2]);
        acc[3] = __builtin_elementwise_fma((floatx2)__builtin_amdgcn_cvt_pk_f32_fp8(f.y, true),  aa, acc[3]);
    }
    s += __shfl_xor(s, 32);
#pragma unroll
    for (int j = 0; j < 4; j++) {
        acc[j].x += __shfl_xor(acc[j].x, 32);
        acc[j].y += __shfl_xor(acc[j].y, 32);
    }
    if (half == 0) {
        float inv = (s > 0.f) ? 1.f / s : 0.f;
        float4 b0 = *(const float4*)&b[sub * 8];
        float4 b1 = *(const float4*)&b[sub * 8 + 4];
        float vals[8];
        vals[0] = acc[0].x * inv + b0.x;
        vals[1] = acc[0].y * inv + b0.y;
        vals[2] = acc[1].x * inv + b0.z;
        vals[3] = acc[1].y * inv + b0.w;
        vals[4] = acc[2].x * inv + b1.x;
        vals[5] = acc[2].y * inv + b1.y;
        vals[6] = acc[3].x * inv + b1.z;
        vals[7] = acc[3].y * inv + b1.w;
        if (FUSEH) {
            us8 xv = *(const us8*)&((const unsigned short*)xs)[(size_t)n * 256 + sub * 8];
            float4 s0v = *(const float4*)&bs2[sub * 8];
            float4 s1v = *(const float4*)&bs2[sub * 8 + 4];
            float sb[8] = {s0v.x, s0v.y, s0v.z, s0v.w, s1v.x, s1v.y, s1v.z, s1v.w};
#pragma unroll
            for (int j = 0; j < 8; j++) {
                float v = vals[j] + bf2f(xv[j]) + sb[j];
                vals[j] = (v > 0.f) ? v : (__expf(v) - 1.f);
            }
        }
        us8 o;
#pragma unroll
        for (int j = 0; j < 8; j++) o[j] = (unsigned short)f2bs(vals[j]);
        *(us8*)&((unsigned short*)rst)[(size_t)n * 256 + sub * 8] = o;
    }
}

// ---- fused attention+aggregation + final layer (layer 2, D=47, bf16 fs) ----
__global__ __launch_bounds__(256)
void attn_final_gen(const bf16* __restrict__ fs, const float* __restrict__ el,
                    const float* __restrict__ er, const float* __restrict__ b,
                    const int* __restrict__ offs, const int* __restrict__ ssrc,
                    const bf16* __restrict__ h2, const float* __restrict__ Ws,
                    const float* __restrict__ bs, float* __restrict__ out,
                    int D, int nd)
{
    __shared__ int slds[4][64];
    __shared__ __align__(16) float alds[4][64][4];
    __shared__ float flds[4][192];
    __shared__ unsigned short hlds[4][256];
    int wave = threadIdx.x >> 6, lane = threadIdx.x & 63;
    int n = blockIdx.x * 4 + wave;               // nd = 2048 = 512*4 exactly
    int HD = HEADS * D;
    int s0 = offs[n], s1 = offs[n + 1];
    int cnt = s1 - s0;
    float4 erv = *(const float4*)&er[(size_t)n * 4];
    const unsigned short* fsu = (const unsigned short*)fs;
    const unsigned short* h2u = (const unsigned short*)h2;

    *(ushort4*)&hlds[wave][lane * 4] = *(const ushort4*)&h2u[(size_t)n * 256 + lane * 4];

    bool act = (4 * lane) < HD;
    int h_[4];
#pragma unroll
    for (int j = 0; j < 4; j++) {
        int e = 4 * lane + j;
        h_[j] = (e < HD) ? (e / D) : 0;
    }
    float acc[4] = {0.f, 0.f, 0.f, 0.f};
    float sp0 = 0.f, sp1 = 0.f, sp2 = 0.f, sp3 = 0.f;

    for (int c0 = 0; c0 < cnt; c0 += 64) {
        int nc = min(cnt - c0, 64);
        if (lane < nc) {
            int sid = ssrc[s0 + c0 + lane];
            float4 ev = *(const float4*)&el[(size_t)sid * 4];
            float e0 = ev.x + erv.x; e0 = (e0 > 0.f) ? e0 : 0.2f * e0;
            float e1 = ev.y + erv.y; e1 = (e1 > 0.f) ? e1 : 0.2f * e1;
            float e2 = ev.z + erv.z; e2 = (e2 > 0.f) ? e2 : 0.2f * e2;
            float e3 = ev.w + erv.w; e3 = (e3 > 0.f) ? e3 : 0.2f * e3;
            float a0 = __expf(fminf(e0, 60.f));
            float a1 = __expf(fminf(e1, 60.f));
            float a2 = __expf(fminf(e2, 60.f));
            float a3 = __expf(fminf(e3, 60.f));
            sp0 += a0; sp1 += a1; sp2 += a2; sp3 += a3;
            slds[wave][lane] = sid;
            alds[wave][lane][0] = a0;
            alds[wave][lane][1] = a1;
            alds[wave][lane][2] = a2;
            alds[wave][lane][3] = a3;
        }
        __builtin_amdgcn_wave_barrier();
        float4 aq[PF]; ushort4 fq[PF];
#pragma unroll
        for (int k = 0; k < PF; k++) {
            if (k < nc) {
                int sid = slds[wave][k];
                aq[k] = *(const float4*)&alds[wave][k][0];
                fq[k] = act ? *(const ushort4*)&fsu[(size_t)sid * HD + 4 * lane]
                            : ushort4{0, 0, 0, 0};
            }
        }
        for (int eb = 0; eb < nc; eb += PF) {
#pragma unroll
            for (int k = 0; k < PF; k++) {
                int e = eb + k;
                if (e >= nc) break;
                float4 a4 = aq[k];
                ushort4 f = fq[k];
                int en = e + PF;
                if (en < nc) {
                    int sid = slds[wave][en];
                    aq[k] = *(const float4*)&alds[wave][en][0];
                    fq[k] = act ? *(const ushort4*)&fsu[(size_t)sid * HD + 4 * lane]
                                : ushort4{0, 0, 0, 0};
                }
                unsigned short fa[4] = {f.x, f.y, f.z, f.w};
#pragma unroll
                for (int j = 0; j < 4; j++) {
                    int hj = h_[j];
                    float av = (hj == 0) ? a4.x : (hj == 1) ? a4.y : (hj == 2) ? a4.z : a4.w;
                    acc[j] += av * bf2f(fa[j]);
                }
            }
        }
        __builtin_amdgcn_wave_barrier();
    }

#pragma unroll
    for (int off = 32; off; off >>= 1) {
        sp0 += __shfl_xor(sp0, off);
        sp1 += __shfl_xor(sp1, off);
        sp2 += __shfl_xor(sp2, off);
        sp3 += __shfl_xor(sp3, off);
    }
    if (act) {
#pragma unroll
        for (int j = 0; j < 4; j++) {
            int e4 = 4 * lane + j;
            int hj = h_[j];
            float sv = (hj == 0) ? sp0 : (hj == 1) ? sp1 : (hj == 2) ? sp2 : sp3;
            float o = (sv > 0.f) ? acc[j] / sv : 0.f;
            flds[wave][e4] = o + b[e4];
        }
    }
    __builtin_amdgcn_wave_barrier();

    const int C = 47;
    int c = lane;
    float v = -INFINITY;
    if (c < C) {
        float mean = 0.25f * (flds[wave][c] + flds[wave][C + c] +
                              flds[wave][2 * C + c] + flds[wave][3 * C + c]);
        float dot = 0.f;
#pragma unroll 4
        for (int k = 0; k < 256; k++)
            dot += bf2f(hlds[wave][k]) * Ws[k * C + c];
        v = mean + dot + bs[c];
    }
    float mx = v;
#pragma unroll
    for (int off = 32; off; off >>= 1) mx = fmaxf(mx, __shfl_xor(mx, off));
    float ex = (c < C) ? __expf(v - mx) : 0.f;
    float sum = ex;
#pragma unroll
    for (int off = 32; off; off >>= 1) sum += __shfl_xor(sum, off);
    if (c < C) out[n * C + c] = v - mx - logf(sum);
}

extern "C" void kernel_launch(void* const* d_in, const int* in_sizes, int n_in,
                              void* d_out, int out_size, void* d_ws, size_t ws_size,
                              hipStream_t stream)
{
    const float* x = (const float*)d_in[0];
    const float* W[3]  = {(const float*)d_in[1],  (const float*)d_in[7],  (const float*)d_in[13]};
    const float* al[3] = {(const float*)d_in[2],  (const float*)d_in[8],  (const float*)d_in[14]};
    const float* ar[3] = {(const float*)d_in[3],  (const float*)d_in[9],  (const float*)d_in[15]};
    const float* bb[3] = {(const float*)d_in[4],  (const float*)d_in[10], (const float*)d_in[16]};
    const float* Ws[3] = {(const float*)d_in[5],  (const float*)d_in[11], (const float*)d_in[17]};
    const float* bs[3] = {(const float*)d_in[6],  (const float*)d_in[12], (const float*)d_in[18]};
    const int* srcp[3] = {(const int*)d_in[19], (const int*)d_in[21], (const int*)d_in[23]};
    const int* dstp[3] = {(const int*)d_in[20], (const int*)d_in[22], (const int*)d_in[24]};

    char* p = (char*)d_ws;
    auto alloc = [&](size_t bytes) -> void* {
        void* r = (void*)p;
        p += (bytes + 255) & ~(size_t)255;
        return r;
    };
    bf16*  fsb   = (bf16*)alloc((size_t)200064 * 256 * 2);   // L0/L1: fp8 view; L2: bf16 view
    bf16*  h1b   = (bf16*)alloc((size_t)50048 * 256 * 2);
    bf16*  h2b   = (bf16*)alloc((size_t)10112 * 256 * 2);
    bf16*  xsb   = (bf16*)alloc((size_t)50048 * 256 * 2);    // skip-GEMM output (xs)
    float* elb   = (float*)alloc((size_t)200064 * 4 * 4);
    float* erb   = (float*)alloc((size_t)50048 * 4 * 4);
    bf16* Wt[3]; bf16* Wst[2];
    Wt[0]  = (bf16*)alloc(256 * 128 * 2);
    Wt[1]  = (bf16*)alloc(256 * 256 * 2);
    Wt[2]  = (bf16*)alloc(256 * 256 * 2);
    Wst[0] = (bf16*)alloc(256 * 128 * 2);
    Wst[1] = (bf16*)alloc(256 * 256 * 2);
    int* offs_all  = (int*)alloc(62051 * 4);
    int* ssrc_all  = (int*)alloc(1300000 * 4);
    int* stage_all = (int*)alloc(1300000 * 4);
    int* blockhist = (int*)alloc(3 * NBIN * NBLK * 4);
    int* binbase   = (int*)alloc(3 * NBIN * NBLK * 4);
    int* bbase     = (int*)alloc(3 * (NBIN + 1) * 4);

    unsigned char* fsb8 = (unsigned char*)fsb;

    const int OOFF[3] = {0, 50001, 60002};
    const int SOFF[3] = {0, 800000, 1200000};

    // weights transpose-cast + per-layer coarse histograms in one dispatch
    precast_all<<<dim3(128, 8), 256, 0, stream>>>(W[0], W[1], W[2], Ws[0], Ws[1],
                                                  Wt[0], Wt[1], Wt[2], Wst[0], Wst[1],
                                                  dstp[0], dstp[1], dstp[2], blockhist);

    scans_fused<<<3, NBIN, 0, stream>>>(blockhist, bbase, offs_all, binbase);
    bin_scatter<<<dim3(NBLK, 3), 256, 0, stream>>>(srcp[0], dstp[0], srcp[1], dstp[1],
                                                   srcp[2], dstp[2], binbase, stage_all);
    bin_expand<<<dim3(NBIN, 3), 256, 0, stream>>>(stage_all, bbase, offs_all, ssrc_all);

    // ---- layer 0 (D=64, cin=128): BIG shape (1563 blocks); attn fuses h1 ----
    gemm_mfma<1, 0, 1, 1, 1, 1, 0><<<dim3(1, 1563), 512, 0, stream>>>(
        x, Wt[0], nullptr, nullptr, al[0], ar[0], elb, erb, fsb8, 200000, 256, 128, 50000,
        Wst[0], xsb);
    attn_agg64<1><<<12500, 256, 0, stream>>>(fsb8, elb, erb, bb[0], offs_all + OOFF[0],
                                             ssrc_all + SOFF[0], xsb, bs[0], h1b, 50000);

    // ---- layer 1 (D=64, cin=256): SMALL shape (782 blocks); attn fuses h2 ----
    gemm_mfma<0, 0, 1, 1, 0, 1, 0><<<dim3(1, 782), 256, 0, stream>>>(
        h1b, Wt[1], nullptr, nullptr, al[1], ar[1], elb, erb, fsb8, 50000, 256, 256, 10000,
        Wst[1], xsb);
    attn_agg64<1><<<2500, 256, 0, stream>>>(fsb8, elb, erb, bb[1], offs_all + OOFF[1],
                                            ssrc_all + SOFF[1], xsb, bs[1], h2b, 10000);

    // ---- layer 2 (D=47, cin=256): SMALL shape (157 blocks); GEMM fuses el/er (EL2) ----
    gemm_mfma<0, 0, 0, 0, 0, 0, 1><<<dim3(1, 157), 256, 0, stream>>>(
        h2b, Wt[2], nullptr, nullptr, al[2], ar[2], elb, erb, fsb, 10000, 188, 256, 2048,
        nullptr, nullptr);
    attn_final_gen<<<512, 256, 0, stream>>>(fsb, elb, erb, bb[2], offs_all + OOFF[2], ssrc_all + SOFF[2],
                                            h2b, Ws[2], bs[2], (float*)d_out, 47, 2048);
}

// Round 18
// 461.188 us; speedup vs baseline: 1.0166x; 1.0166x over previous
//
#include <hip/hip_runtime.h>
#include <hip/hip_bf16.h>
#include <cmath>

#define HEADS 4
typedef __hip_bfloat16 bf16;
typedef short short8 __attribute__((ext_vector_type(8)));
typedef unsigned short us8 __attribute__((ext_vector_type(8)));
typedef float floatx4 __attribute__((ext_vector_type(4)));
typedef float floatx2 __attribute__((ext_vector_type(2)));
typedef unsigned int u32;

__device__ inline float bf2f(unsigned short u) {
    union { unsigned u; float f; } c; c.u = ((unsigned)u) << 16; return c.f;
}
__device__ inline short f2bs(float f) {
    bf16 h = __float2bfloat16(f);
    return *reinterpret_cast<short*>(&h);
}
__device__ __forceinline__ unsigned pack_bf16(float a, float b) {
    return (((unsigned)(unsigned short)f2bs(b)) << 16) | (unsigned short)f2bs(a);
}
// pack 4 floats -> 4 fp8 e4m3 bytes (OCP, gfx950 HW cvt)
__device__ __forceinline__ unsigned pack_fp8x4(float a, float b, float c, float d) {
    unsigned lo = __builtin_amdgcn_cvt_pk_fp8_f32(a, b, 0, false);
    return __builtin_amdgcn_cvt_pk_fp8_f32(c, d, lo, true);
}

// async 16B global->LDS (DMA, no VGPR round-trip). LDS dest: wave-uniform base + lane*16.
__device__ __forceinline__ void ld_lds16(const void* g, void* l) {
    __builtin_amdgcn_global_load_lds((const __attribute__((address_space(1))) u32*)g,
                                     (__attribute__((address_space(3))) u32*)l, 16, 0, 0);
}

// ---- problem constants ----
__device__ const int g_ND[3]   = {50000, 10000, 2048};
__device__ const int g_OOFF[3] = {0, 50001, 60002};
__device__ const int g_NE[3]   = {800000, 400000, 100000};
__device__ const int g_SOFF[3] = {0, 800000, 1200000};
__device__ const int g_S[3]    = {391, 79, 16};

#define NBIN 128
#define NBLK 128
#define MAXB 8192
#define MAXS 391
#define PF 4

// ------- weights transpose-cast (5 slabs) + per-layer coarse histograms, one dispatch -------
__global__ void precast_all(const float* __restrict__ W0, const float* __restrict__ W1,
                            const float* __restrict__ W2, const float* __restrict__ W3,
                            const float* __restrict__ W4,
                            bf16* __restrict__ B0, bf16* __restrict__ B1, bf16* __restrict__ B2,
                            bf16* __restrict__ B3, bf16* __restrict__ B4,
                            const int* __restrict__ d0, const int* __restrict__ d1,
                            const int* __restrict__ d2, int* __restrict__ blockhist)
{
    int y = blockIdx.y;
    if (y >= 5) {
        int l = y - 5;
        const int* dst = (l == 0) ? d0 : (l == 1) ? d1 : d2;
        int ne = g_NE[l], S = g_S[l];
        __shared__ int h[NBIN];
        for (int i = threadIdx.x; i < NBIN; i += blockDim.x) h[i] = 0;
        __syncthreads();
        int per = (ne + NBLK - 1) / NBLK;
        int st = blockIdx.x * per;
        int en = min(st + per, ne);
        for (int i = st + threadIdx.x; i < en; i += blockDim.x)
            atomicAdd(&h[dst[i] / S], 1);
        __syncthreads();
        for (int i = threadIdx.x; i < NBIN; i += blockDim.x)
            blockhist[(l * NBIN + i) * NBLK + blockIdx.x] = h[i];
        return;
    }
    const int Ks[5] = {128, 256, 256, 128, 256};
    const int Ns[5] = {256, 256, 188, 256, 256};
    const float* W = (y == 0) ? W0 : (y == 1) ? W1 : (y == 2) ? W2 : (y == 3) ? W3 : W4;
    bf16* B = (y == 0) ? B0 : (y == 1) ? B1 : (y == 2) ? B2 : (y == 3) ? B3 : B4;
    int K = Ks[y], N = Ns[y], sz = K * N;
    for (int i = blockIdx.x * blockDim.x + threadIdx.x; i < sz; i += gridDim.x * blockDim.x) {
        int n = i / K, k = i % K;
        B[i] = __float2bfloat16(W[(size_t)k * N + n]);
    }
}

// -------- MFMA GEMM: C[M,N] = A[M,K] @ Bt[N,K]^T, BN=256 BK=64 (shape-templated) -----
// BIG=1: 512 thr, BM=128 (8 waves, 2Mx4N) -- best for large grids (L0).
// BIG=0: 256 thr, BM=64  (4 waves, 1Mx4N) -- best for small grids (L1/L2, more blocks).
// Swapped-operand MFMA: acc[mt][nt][e] = C[row0+wm+mt*16+r][wn+nt*16+q*4+e].
// AF32: A f32, cast fused into staging. SKIP: fused skip half-pass. EL2: D=47 el/er.
template<int BIG, int FUSE, int EL, int OUT8, int AF32, int SKIP, int EL2>
__global__ __launch_bounds__(BIG ? 512 : 256)
void gemm_mfma(const void* __restrict__ Ain, const bf16* __restrict__ Bt,
               const bf16* __restrict__ add, const float* __restrict__ bias,
               const float* __restrict__ al, const float* __restrict__ ar,
               float* __restrict__ el, float* __restrict__ er,
               void* __restrict__ Cb, int M, int N, int K, int nd,
               const bf16* __restrict__ Bt2, bf16* __restrict__ Cb2)
{
    const int BK = 64;
    const int THREADS = BIG ? 512 : 256;
    const int BM = BIG ? 128 : 64;
    const int SR = THREADS / 8;          // staging rows per ld_lds16 call
    const int NBC = 256 / SR;            // B staging calls
    __shared__ short As[BM * BK];        // 16 KB / 8 KB (EL2 reuses as float)
    __shared__ short Bs[256 * BK];       // 32 KB
    int tid = threadIdx.x;
    int wave = tid >> 6, lane = tid & 63;
    int q = lane >> 4, r = lane & 15;
    int row0 = blockIdx.y * BM;
    int wm = BIG ? ((wave >> 2) * 64) : 0;
    int wn = (wave & 3) * 64;

    const short* B16 = (const short*)Bt;
    int srow = tid >> 3;                       // 0..SR-1 rows per staging call
    int scol = ((tid & 7) ^ (srow & 7)) * 8;   // inverse-swizzled source granule
    const short* ga0s = nullptr; const short* ga1s = nullptr;
    const float* gaf0s = nullptr; const float* gaf1s = nullptr;
    if (AF32) {
        int arow0 = min(row0 + srow, M - 1);
        int arow1 = min(row0 + SR + srow, M - 1);
        gaf0s = (const float*)Ain + (size_t)arow0 * K + scol;
        gaf1s = (const float*)Ain + (size_t)arow1 * K + scol;
    } else {
        const short* A16 = (const short*)Ain;
        ga0s = A16 + (size_t)(row0 + srow) * K + scol;
        ga1s = ga0s + (size_t)SR * K;
    }
    char* la = (char*)As + tid * 16;
    char* lb = (char*)Bs + tid * 16;

    floatx4 zero = {0.f, 0.f, 0.f, 0.f};
    floatx4 acc[4][4];
#pragma unroll
    for (int i = 0; i < 4; i++)
#pragma unroll
        for (int j = 0; j < 4; j++) acc[i][j] = zero;

    {
        const short* gb = B16 + (size_t)srow * K + scol;
        const short* ga0 = ga0s; const short* ga1 = ga1s;
        const float* gaf0 = gaf0s; const float* gaf1 = gaf1s;
        for (int k0 = 0; k0 < K; k0 += BK) {
#pragma unroll
            for (int j = 0; j < NBC; j++)
                ld_lds16(gb + (size_t)(j * SR) * K, lb + j * THREADS * 16);
            gb += BK;
            if (AF32) {
                float4 a0 = *(const float4*)gaf0;
                float4 a1 = *(const float4*)(gaf0 + 4);
                float4 b0 = *(const float4*)gaf1;
                float4 b1 = *(const float4*)(gaf1 + 4);
                uint4 w0 = {pack_bf16(a0.x, a0.y), pack_bf16(a0.z, a0.w),
                            pack_bf16(a1.x, a1.y), pack_bf16(a1.z, a1.w)};
                uint4 w1 = {pack_bf16(b0.x, b0.y), pack_bf16(b0.z, b0.w),
                            pack_bf16(b1.x, b1.y), pack_bf16(b1.z, b1.w)};
                *(uint4*)la = w0;
                *(uint4*)(la + THREADS * 16) = w1;
                gaf0 += BK; gaf1 += BK;
            } else {
                ld_lds16(ga0, la);
                ld_lds16(ga1, la + THREADS * 16);
                ga0 += BK; ga1 += BK;
            }
            __syncthreads();
#pragma unroll
            for (int ks = 0; ks < 2; ks++) {
                int gr = (((ks << 2) | q) ^ (r & 7)) * 8;
                short8 af[4], bfr[4];
#pragma unroll
                for (int mt = 0; mt < 4; mt++)
                    af[mt] = *(short8*)&As[(wm + mt * 16 + r) * BK + gr];
#pragma unroll
                for (int nt = 0; nt < 4; nt++)
                    bfr[nt] = *(short8*)&Bs[(wn + nt * 16 + r) * BK + gr];
#pragma unroll
                for (int mt = 0; mt < 4; mt++)
#pragma unroll
                    for (int nt = 0; nt < 4; nt++)
                        acc[mt][nt] = __builtin_amdgcn_mfma_f32_16x16x32_bf16(bfr[nt], af[mt], acc[mt][nt], 0, 0, 0);
            }
            __syncthreads();
        }
    }

    // epilogue: per (mt,nt) lane holds C[grow][n0..n0+3], grow = row0+wm+mt*16+r
#pragma unroll
    for (int mt = 0; mt < 4; mt++) {
        int grow = row0 + wm + mt * 16 + r;
        if (grow >= M) continue;
#pragma unroll
        for (int nt = 0; nt < 4; nt++) {
            int n0 = wn + nt * 16 + q * 4;
            floatx4 v = acc[mt][nt];
            if (FUSE == 1) {
                ushort4 ad = *(const ushort4*)&add[(size_t)grow * N + n0];
                float4 bi = *(const float4*)&bias[n0];
                v[0] += bf2f(ad.x) + bi.x;
                v[1] += bf2f(ad.y) + bi.y;
                v[2] += bf2f(ad.z) + bi.z;
                v[3] += bf2f(ad.w) + bi.w;
#pragma unroll
                for (int e = 0; e < 4; e++) v[e] = (v[e] > 0.f) ? v[e] : (__expf(v[e]) - 1.f);
            }
            if (OUT8) {
                *(u32*)((unsigned char*)Cb + (size_t)grow * N + n0) =
                    pack_fp8x4(v[0], v[1], v[2], v[3]);
            } else if (n0 + 3 < N) {      // bounds-guard packed store (N=188 layer 2)
                uint2 o = {pack_bf16(v[0], v[1]), pack_bf16(v[2], v[3])};
                *(uint2*)((unsigned short*)Cb + (size_t)grow * N + n0) = o;
            } else {
#pragma unroll
                for (int e = 0; e < 4; e++)
                    if (n0 + e < N)
                        ((unsigned short*)Cb)[(size_t)grow * N + n0 + e] = (unsigned short)f2bs(v[e]);
            }
        }
    }

    if (EL) {
        int head = wave & 3;   // wn == head*64
#pragma unroll
        for (int mt = 0; mt < 4; mt++) {
            float pl = 0.f, pr = 0.f;
#pragma unroll
            for (int nt = 0; nt < 4; nt++) {
                int nn = nt * 16 + q * 4;
                float4 av = *(const float4*)&al[head * 64 + nn];
                float4 rv = *(const float4*)&ar[head * 64 + nn];
                floatx4 v = acc[mt][nt];
                pl += v[0] * av.x + v[1] * av.y + v[2] * av.z + v[3] * av.w;
                pr += v[0] * rv.x + v[1] * rv.y + v[2] * rv.z + v[3] * rv.w;
            }
            pl += __shfl_xor(pl, 16); pl += __shfl_xor(pl, 32);
            pr += __shfl_xor(pr, 16); pr += __shfl_xor(pr, 32);
            int grow = row0 + wm + mt * 16 + r;
            if (lane < 16 && grow < M) {
                el[grow * 4 + head] = pl;
                if (grow < nd) er[grow * 4 + head] = pr;
            }
        }
    }

    // ---- EL2: D=47 el/er fused epilogue (layer 2). al/ar flat [188]. ----
    if (EL2) {
        float* part = (float*)As;   // [row 0..BM-1][wnidx 0..3][h 0..3][2] = BM*32 f32
        int wnidx = wave & 3;
#pragma unroll
        for (int mt = 0; mt < 4; mt++) {
            float pl[4] = {0.f, 0.f, 0.f, 0.f};
            float pr[4] = {0.f, 0.f, 0.f, 0.f};
#pragma unroll
            for (int nt = 0; nt < 4; nt++) {
                int n0 = wn + nt * 16 + q * 4;
                floatx4 v = acc[mt][nt];
#pragma unroll
                for (int e = 0; e < 4; e++) {
                    int c = n0 + e;
                    if (c < 188) {
                        int h = (c >= 141) ? 3 : (c >= 94) ? 2 : (c >= 47) ? 1 : 0;
                        pl[h] += v[e] * al[c];
                        pr[h] += v[e] * ar[c];
                    }
                }
            }
#pragma unroll
            for (int h = 0; h < 4; h++) {
                pl[h] += __shfl_xor(pl[h], 16); pl[h] += __shfl_xor(pl[h], 32);
                pr[h] += __shfl_xor(pr[h], 16); pr[h] += __shfl_xor(pr[h], 32);
            }
            if (lane < 16) {
                int row = wm + mt * 16 + r;
#pragma unroll
                for (int h = 0; h < 4; h++) {
                    part[row * 32 + wnidx * 8 + h * 2 + 0] = pl[h];
                    part[row * 32 + wnidx * 8 + h * 2 + 1] = pr[h];
                }
            }
        }
        __syncthreads();
        int row = tid >> 2, h = tid & 3;   // THREADS = BM rows x 4 heads
        int grow = row0 + row;
        if (grow < M) {
            float ev = part[row * 32 + 0 + h * 2]     + part[row * 32 + 8 + h * 2]
                     + part[row * 32 + 16 + h * 2]    + part[row * 32 + 24 + h * 2];
            float rv = part[row * 32 + 0 + h * 2 + 1] + part[row * 32 + 8 + h * 2 + 1]
                     + part[row * 32 + 16 + h * 2 + 1]+ part[row * 32 + 24 + h * 2 + 1];
            el[grow * 4 + h] = ev;
            if (grow < nd) er[grow * 4 + h] = rv;
        }
    }

    // ---- skip half-pass: xs = A @ Bt2^T (bf16), rows < nd only ----
    if (SKIP) {
        if (row0 >= nd) return;
#pragma unroll
        for (int i = 0; i < 4; i++)
#pragma unroll
            for (int j = 0; j < 4; j++) acc[i][j] = zero;
        const short* gb2 = (const short*)Bt2 + (size_t)srow * K + scol;
        const short* ga0 = ga0s; const short* ga1 = ga1s;
        const float* gaf0 = gaf0s; const float* gaf1 = gaf1s;
        for (int k0 = 0; k0 < K; k0 += BK) {
#pragma unroll
            for (int j = 0; j < NBC; j++)
                ld_lds16(gb2 + (size_t)(j * SR) * K, lb + j * THREADS * 16);
            gb2 += BK;
            if (AF32) {
                float4 a0 = *(const float4*)gaf0;
                float4 a1 = *(const float4*)(gaf0 + 4);
                float4 b0 = *(const float4*)gaf1;
                float4 b1 = *(const float4*)(gaf1 + 4);
                uint4 w0 = {pack_bf16(a0.x, a0.y), pack_bf16(a0.z, a0.w),
                            pack_bf16(a1.x, a1.y), pack_bf16(a1.z, a1.w)};
                uint4 w1 = {pack_bf16(b0.x, b0.y), pack_bf16(b0.z, b0.w),
                            pack_bf16(b1.x, b1.y), pack_bf16(b1.z, b1.w)};
                *(uint4*)la = w0;
                *(uint4*)(la + THREADS * 16) = w1;
                gaf0 += BK; gaf1 += BK;
            } else {
                ld_lds16(ga0, la);
                ld_lds16(ga1, la + THREADS * 16);
                ga0 += BK; ga1 += BK;
            }
            __syncthreads();
#pragma unroll
            for (int ks = 0; ks < 2; ks++) {
                int gr = (((ks << 2) | q) ^ (r & 7)) * 8;
                short8 af[4], bfr[4];
#pragma unroll
                for (int mt = 0; mt < 4; mt++)
                    af[mt] = *(short8*)&As[(wm + mt * 16 + r) * BK + gr];
#pragma unroll
                for (int nt = 0; nt < 4; nt++)
                    bfr[nt] = *(short8*)&Bs[(wn + nt * 16 + r) * BK + gr];
#pragma unroll
                for (int mt = 0; mt < 4; mt++)
#pragma unroll
                    for (int nt = 0; nt < 4; nt++)
                        acc[mt][nt] = __builtin_amdgcn_mfma_f32_16x16x32_bf16(bfr[nt], af[mt], acc[mt][nt], 0, 0, 0);
            }
            __syncthreads();
        }
#pragma unroll
        for (int mt = 0; mt < 4; mt++) {
            int grow = row0 + wm + mt * 16 + r;
            if (grow >= nd) continue;
#pragma unroll
            for (int nt = 0; nt < 4; nt++) {
                int n0 = wn + nt * 16 + q * 4;
                floatx4 v = acc[mt][nt];
                uint2 o = {pack_bf16(v[0], v[1]), pack_bf16(v[2], v[3])};
                *(uint2*)((unsigned short*)Cb2 + (size_t)grow * 256 + n0) = o;
            }
        }
    }
}

// ---------------- two-level radix partition by dst (hist fused into precast) ----------------
__global__ void coarse_scan(const int* __restrict__ blockhist, int* __restrict__ bbase,
                            int* __restrict__ offs)
{
    int l = blockIdx.x;
    int t = threadIdx.x;   // 0..127
    __shared__ int s[NBIN];
    int tot = 0;
    for (int k = 0; k < NBLK; k++) tot += blockhist[(l * NBIN + t) * NBLK + k];
    s[t] = tot;
    __syncthreads();
    for (int off = 1; off < NBIN; off <<= 1) {
        int a = (t >= off) ? s[t - off] : 0;
        __syncthreads();
        s[t] += a;
        __syncthreads();
    }
    bbase[l * (NBIN + 1) + t + 1] = s[t];
    if (t == 0) {
        bbase[l * (NBIN + 1)] = 0;
        offs[g_OOFF[l] + g_ND[l]] = g_NE[l];
    }
}

__global__ void bin_scan(const int* __restrict__ blockhist, const int* __restrict__ bbase,
                         int* __restrict__ base)
{
    int l = blockIdx.y, bin = blockIdx.x;
    int t = threadIdx.x;  // 0..NBLK-1
    __shared__ int s[NBLK];
    int v = blockhist[(l * NBIN + bin) * NBLK + t];
    s[t] = v;
    __syncthreads();
    for (int off = 1; off < NBLK; off <<= 1) {
        int a = (t >= off) ? s[t - off] : 0;
        __syncthreads();
        s[t] += a;
        __syncthreads();
    }
    base[(l * NBIN + bin) * NBLK + t] = bbase[l * (NBIN + 1) + bin] + s[t] - v;
}

__global__ __launch_bounds__(256)
void bin_scatter(const int* __restrict__ s0, const int* __restrict__ d0,
                 const int* __restrict__ s1, const int* __restrict__ d1,
                 const int* __restrict__ s2, const int* __restrict__ d2,
                 const int* __restrict__ base, int* __restrict__ stage)
{
    int l = blockIdx.y;
    const int* src = (l == 0) ? s0 : (l == 1) ? s1 : s2;
    const int* dst = (l == 0) ? d0 : (l == 1) ? d1 : d2;
    int ne = g_NE[l], S = g_S[l], soff = g_SOFF[l];
    __shared__ int cur[NBIN];
    for (int i = threadIdx.x; i < NBIN; i += blockDim.x)
        cur[i] = base[(l * NBIN + i) * NBLK + blockIdx.x];
    __syncthreads();
    int per = (ne + NBLK - 1) / NBLK;
    int st = blockIdx.x * per;
    int en = min(st + per, ne);
    for (int i = st + threadIdx.x; i < en; i += blockDim.x) {
        int dv = dst[i];
        int b = dv / S;
        int ldst = dv - b * S;
        int p = atomicAdd(&cur[b], 1);
        stage[soff + p] = src[i] | (ldst << 18);
    }
}

__global__ __launch_bounds__(256)
void bin_expand(const int* __restrict__ stage, const int* __restrict__ bbase,
                int* __restrict__ offs, int* __restrict__ ssrc)
{
    int l = blockIdx.y, b = blockIdx.x;
    int S = g_S[l], nd = g_ND[l], ooff = g_OOFF[l], soff = g_SOFF[l];
    int dlo = b * S;
    if (dlo >= nd) return;
    int dhi = min(dlo + S, nd);
    int base = bbase[l * (NBIN + 1) + b];
    int end  = bbase[l * (NBIN + 1) + b + 1];
    int cnt  = end - base;
    int tid = threadIdx.x;
    __shared__ int sdata[MAXB];
    __shared__ int outb[MAXB];
    __shared__ int lh[512];
    __shared__ int lcur[MAXS];
    lh[tid] = 0; lh[tid + 256] = 0;
    __syncthreads();
    if (cnt <= MAXB) {
        for (int i = tid; i < cnt; i += 256) {
            int v = stage[soff + base + i];
            sdata[i] = v;
            atomicAdd(&lh[v >> 18], 1);
        }
        __syncthreads();
        for (int off = 1; off < 512; off <<= 1) {
            int a0 = (tid >= off) ? lh[tid - off] : 0;
            int a1 = lh[tid + 256 - off];
            __syncthreads();
            lh[tid] += a0; lh[tid + 256] += a1;
            __syncthreads();
        }
        for (int d = tid; d < dhi - dlo; d += 256) {
            int ex = (d == 0) ? 0 : lh[d - 1];
            offs[ooff + dlo + d] = base + ex;
            lcur[d] = ex;
        }
        __syncthreads();
        for (int i = tid; i < cnt; i += 256) {
            int v = sdata[i];
            int p = atomicAdd(&lcur[v >> 18], 1);
            outb[p] = v & 0x3FFFF;
        }
        __syncthreads();
        for (int i = tid; i < cnt; i += 256)
            ssrc[soff + base + i] = outb[i];
    } else {
        for (int i = tid; i < cnt; i += 256)
            atomicAdd(&lh[stage[soff + base + i] >> 18], 1);
        __syncthreads();
        for (int off = 1; off < 512; off <<= 1) {
            int a0 = (tid >= off) ? lh[tid - off] : 0;
            int a1 = lh[tid + 256 - off];
            __syncthreads();
            lh[tid] += a0; lh[tid + 256] += a1;
            __syncthreads();
        }
        for (int d = tid; d < dhi - dlo; d += 256) {
            int ex = (d == 0) ? 0 : lh[d - 1];
            offs[ooff + dlo + d] = base + ex;
            lcur[d] = ex;
        }
        __syncthreads();
        for (int i = tid; i < cnt; i += 256) {
            int v = stage[soff + base + i];
            int p = atomicAdd(&lcur[v >> 18], 1);
            ssrc[soff + base + p] = v & 0x3FFFF;
        }
    }
}

// ---------------- fused attention+aggregation, D=64 (HD=256), fp8 fs rows ----------------
template<int FUSEH>
__global__ __launch_bounds__(256)
void attn_agg64(const unsigned char* __restrict__ fs8, const float* __restrict__ el,
                const float* __restrict__ er, const float* __restrict__ b,
                const int* __restrict__ offs, const int* __restrict__ ssrc,
                const bf16* __restrict__ xs, const float* __restrict__ bs2,
                bf16* __restrict__ rst, int nd)
{
    int wave = threadIdx.x >> 6, lane = threadIdx.x & 63;
    int n = blockIdx.x * 4 + wave;
    if (n >= nd) return;
    int s0 = offs[n], s1 = offs[n + 1];
    float4 erv = *(const float4*)&er[(size_t)n * 4];
    int half = lane >> 5, sub = lane & 31, head = sub >> 3;
    float eh = (head == 0) ? erv.x : (head == 1) ? erv.y : (head == 2) ? erv.z : erv.w;

    floatx2 acc[4];
#pragma unroll
    for (int j = 0; j < 4; j++) acc[j] = (floatx2){0.f, 0.f};
    float s = 0.f;

    int cnt = s1 - s0;
    int npairs = cnt >> 1;
    int i = s0 + half;
    if (npairs > 0) {
        int sid = ssrc[i];
        float ev = el[(size_t)sid * 4 + head];
        uint2 f = *(const uint2*)&fs8[(size_t)sid * 256 + sub * 8];
        for (int p = 1; p < npairs; p++) {
            i += 2;
            int sid2 = ssrc[i];
            float ev2 = el[(size_t)sid2 * 4 + head];
            uint2 f2 = *(const uint2*)&fs8[(size_t)sid2 * 256 + sub * 8];
            float e = ev + eh; e = (e > 0.f) ? e : 0.2f * e;
            float a = __expf(fminf(e, 60.f));
            s += a;
            floatx2 aa = {a, a};
            acc[0] = __builtin_elementwise_fma((floatx2)__builtin_amdgcn_cvt_pk_f32_fp8(f.x, false), aa, acc[0]);
            acc[1] = __builtin_elementwise_fma((floatx2)__builtin_amdgcn_cvt_pk_f32_fp8(f.x, true),  aa, acc[1]);
            acc[2] = __builtin_elementwise_fma((floatx2)__builtin_amdgcn_cvt_pk_f32_fp8(f.y, false), aa, acc[2]);
            acc[3] = __builtin_elementwise_fma((floatx2)__builtin_amdgcn_cvt_pk_f32_fp8(f.y, true),  aa, acc[3]);
            ev = ev2; f = f2;
        }
        float e = ev + eh; e = (e > 0.f) ? e : 0.2f * e;
        float a = __expf(fminf(e, 60.f));
        s += a;
        floatx2 aa = {a, a};
        acc[0] = __builtin_elementwise_fma((floatx2)__builtin_amdgcn_cvt_pk_f32_fp8(f.x, false), aa, acc[0]);
        acc[1] = __builtin_elementwise_fma((floatx2)__builtin_amdgcn_cvt_pk_f32_fp8(f.x, true),  aa, acc[1]);
        acc[2] = __builtin_elementwise_fma((floatx2)__builtin_amdgcn_cvt_pk_f32_fp8(f.y, false), aa, acc[2]);
        acc[3] = __builtin_elementwise_fma((floatx2)__builtin_amdgcn_cvt_pk_f32_fp8(f.y, true),  aa, acc[3]);
    }
    if (cnt & 1) {
        int idx = s1 - 1;
        int sid = ssrc[idx];
        float ev = el[(size_t)sid * 4 + head];
        uint2 f = *(const uint2*)&fs8[(size_t)sid * 256 + sub * 8];
        float e = ev + eh; e = (e > 0.f) ? e : 0.2f * e;
        float a = __expf(fminf(e, 60.f));
        if (half) a = 0.f;
        s += a;
        floatx2 aa = {a, a};
        acc[0] = __builtin_elementwise_fma((floatx2)__builtin_amdgcn_cvt_pk_f32_fp8(f.x, false), aa, acc[0]);
        acc[1] = __builtin_elementwise_fma((floatx2)__builtin_amdgcn_cvt_pk_f32_fp8(f.x, true),  aa, acc[1]);
        acc[2] = __builtin_elementwise_fma((floatx2)__builtin_amdgcn_cvt_pk_f32_fp8(f.y, false), aa, acc[2]);
        acc[3] = __builtin_elementwise_fma((floatx2)__builtin_amdgcn_cvt_pk_f32_fp8(f.y, true),  aa, acc[3]);
    }
    s += __shfl_xor(s, 32);
#pragma unroll
    for (int j = 0; j < 4; j++) {
        acc[j].x += __shfl_xor(acc[j].x, 32);
        acc[j].y += __shfl_xor(acc[j].y, 32);
    }
    if (half == 0) {
        float inv = (s > 0.f) ? 1.f / s : 0.f;
        float4 b0 = *(const float4*)&b[sub * 8];
        float4 b1 = *(const float4*)&b[sub * 8 + 4];
        float vals[8];
        vals[0] = acc[0].x * inv + b0.x;
        vals[1] = acc[0].y * inv + b0.y;
        vals[2] = acc[1].x * inv + b0.z;
        vals[3] = acc[1].y * inv + b0.w;
        vals[4] = acc[2].x * inv + b1.x;
        vals[5] = acc[2].y * inv + b1.y;
        vals[6] = acc[3].x * inv + b1.z;
        vals[7] = acc[3].y * inv + b1.w;
        if (FUSEH) {
            us8 xv = *(const us8*)&((const unsigned short*)xs)[(size_t)n * 256 + sub * 8];
            float4 s0v = *(const float4*)&bs2[sub * 8];
            float4 s1v = *(const float4*)&bs2[sub * 8 + 4];
            float sb[8] = {s0v.x, s0v.y, s0v.z, s0v.w, s1v.x, s1v.y, s1v.z, s1v.w};
#pragma unroll
            for (int j = 0; j < 8; j++) {
                float v = vals[j] + bf2f(xv[j]) + sb[j];
                vals[j] = (v > 0.f) ? v : (__expf(v) - 1.f);
            }
        }
        us8 o;
#pragma unroll
        for (int j = 0; j < 8; j++) o[j] = (unsigned short)f2bs(vals[j]);
        *(us8*)&((unsigned short*)rst)[(size_t)n * 256 + sub * 8] = o;
    }
}

// ---- fused attention+aggregation + final layer (layer 2, D=47, bf16 fs) ----
__global__ __launch_bounds__(256)
void attn_final_gen(const bf16* __restrict__ fs, const float* __restrict__ el,
                    const float* __restrict__ er, const float* __restrict__ b,
                    const int* __restrict__ offs, const int* __restrict__ ssrc,
                    const bf16* __restrict__ h2, const float* __restrict__ Ws,
                    const float* __restrict__ bs, float* __restrict__ out,
                    int D, int nd)
{
    __shared__ int slds[4][64];
    __shared__ __align__(16) float alds[4][64][4];
    __shared__ float flds[4][192];
    __shared__ unsigned short hlds[4][256];
    int wave = threadIdx.x >> 6, lane = threadIdx.x & 63;
    int n = blockIdx.x * 4 + wave;               // nd = 2048 = 512*4 exactly
    int HD = HEADS * D;
    int s0 = offs[n], s1 = offs[n + 1];
    int cnt = s1 - s0;
    float4 erv = *(const float4*)&er[(size_t)n * 4];
    const unsigned short* fsu = (const unsigned short*)fs;
    const unsigned short* h2u = (const unsigned short*)h2;

    *(ushort4*)&hlds[wave][lane * 4] = *(const ushort4*)&h2u[(size_t)n * 256 + lane * 4];

    bool act = (4 * lane) < HD;
    int h_[4];
#pragma unroll
    for (int j = 0; j < 4; j++) {
        int e = 4 * lane + j;
        h_[j] = (e < HD) ? (e / D) : 0;
    }
    float acc[4] = {0.f, 0.f, 0.f, 0.f};
    float sp0 = 0.f, sp1 = 0.f, sp2 = 0.f, sp3 = 0.f;

    for (int c0 = 0; c0 < cnt; c0 += 64) {
        int nc = min(cnt - c0, 64);
        if (lane < nc) {
            int sid = ssrc[s0 + c0 + lane];
            float4 ev = *(const float4*)&el[(size_t)sid * 4];
            float e0 = ev.x + erv.x; e0 = (e0 > 0.f) ? e0 : 0.2f * e0;
            float e1 = ev.y + erv.y; e1 = (e1 > 0.f) ? e1 : 0.2f * e1;
            float e2 = ev.z + erv.z; e2 = (e2 > 0.f) ? e2 : 0.2f * e2;
            float e3 = ev.w + erv.w; e3 = (e3 > 0.f) ? e3 : 0.2f * e3;
            float a0 = __expf(fminf(e0, 60.f));
            float a1 = __expf(fminf(e1, 60.f));
            float a2 = __expf(fminf(e2, 60.f));
            float a3 = __expf(fminf(e3, 60.f));
            sp0 += a0; sp1 += a1; sp2 += a2; sp3 += a3;
            slds[wave][lane] = sid;
            alds[wave][lane][0] = a0;
            alds[wave][lane][1] = a1;
            alds[wave][lane][2] = a2;
            alds[wave][lane][3] = a3;
        }
        __builtin_amdgcn_wave_barrier();
        float4 aq[PF]; ushort4 fq[PF];
#pragma unroll
        for (int k = 0; k < PF; k++) {
            if (k < nc) {
                int sid = slds[wave][k];
                aq[k] = *(const float4*)&alds[wave][k][0];
                fq[k] = act ? *(const ushort4*)&fsu[(size_t)sid * HD + 4 * lane]
                            : ushort4{0, 0, 0, 0};
            }
        }
        for (int eb = 0; eb < nc; eb += PF) {
#pragma unroll
            for (int k = 0; k < PF; k++) {
                int e = eb + k;
                if (e >= nc) break;
                float4 a4 = aq[k];
                ushort4 f = fq[k];
                int en = e + PF;
                if (en < nc) {
                    int sid = slds[wave][en];
                    aq[k] = *(const float4*)&alds[wave][en][0];
                    fq[k] = act ? *(const ushort4*)&fsu[(size_t)sid * HD + 4 * lane]
                                : ushort4{0, 0, 0, 0};
                }
                unsigned short fa[4] = {f.x, f.y, f.z, f.w};
#pragma unroll
                for (int j = 0; j < 4; j++) {
                    int hj = h_[j];
                    float av = (hj == 0) ? a4.x : (hj == 1) ? a4.y : (hj == 2) ? a4.z : a4.w;
                    acc[j] += av * bf2f(fa[j]);
                }
            }
        }
        __builtin_amdgcn_wave_barrier();
    }

#pragma unroll
    for (int off = 32; off; off >>= 1) {
        sp0 += __shfl_xor(sp0, off);
        sp1 += __shfl_xor(sp1, off);
        sp2 += __shfl_xor(sp2, off);
        sp3 += __shfl_xor(sp3, off);
    }
    if (act) {
#pragma unroll
        for (int j = 0; j < 4; j++) {
            int e4 = 4 * lane + j;
            int hj = h_[j];
            float sv = (hj == 0) ? sp0 : (hj == 1) ? sp1 : (hj == 2) ? sp2 : sp3;
            float o = (sv > 0.f) ? acc[j] / sv : 0.f;
            flds[wave][e4] = o + b[e4];
        }
    }
    __builtin_amdgcn_wave_barrier();

    const int C = 47;
    int c = lane;
    float v = -INFINITY;
    if (c < C) {
        float mean = 0.25f * (flds[wave][c] + flds[wave][C + c] +
                              flds[wave][2 * C + c] + flds[wave][3 * C + c]);
        float dot = 0.f;
#pragma unroll 4
        for (int k = 0; k < 256; k++)
            dot += bf2f(hlds[wave][k]) * Ws[k * C + c];
        v = mean + dot + bs[c];
    }
    float mx = v;
#pragma unroll
    for (int off = 32; off; off >>= 1) mx = fmaxf(mx, __shfl_xor(mx, off));
    float ex = (c < C) ? __expf(v - mx) : 0.f;
    float sum = ex;
#pragma unroll
    for (int off = 32; off; off >>= 1) sum += __shfl_xor(sum, off);
    if (c < C) out[n * C + c] = v - mx - logf(sum);
}

extern "C" void kernel_launch(void* const* d_in, const int* in_sizes, int n_in,
                              void* d_out, int out_size, void* d_ws, size_t ws_size,
                              hipStream_t stream)
{
    const float* x = (const float*)d_in[0];
    const float* W[3]  = {(const float*)d_in[1],  (const float*)d_in[7],  (const float*)d_in[13]};
    const float* al[3] = {(const float*)d_in[2],  (const float*)d_in[8],  (const float*)d_in[14]};
    const float* ar[3] = {(const float*)d_in[3],  (const float*)d_in[9],  (const float*)d_in[15]};
    const float* bb[3] = {(const float*)d_in[4],  (const float*)d_in[10], (const float*)d_in[16]};
    const float* Ws[3] = {(const float*)d_in[5],  (const float*)d_in[11], (const float*)d_in[17]};
    const float* bs[3] = {(const float*)d_in[6],  (const float*)d_in[12], (const float*)d_in[18]};
    const int* srcp[3] = {(const int*)d_in[19], (const int*)d_in[21], (const int*)d_in[23]};
    const int* dstp[3] = {(const int*)d_in[20], (const int*)d_in[22], (const int*)d_in[24]};

    char* p = (char*)d_ws;
    auto alloc = [&](size_t bytes) -> void* {
        void* r = (void*)p;
        p += (bytes + 255) & ~(size_t)255;
        return r;
    };
    bf16*  fsb   = (bf16*)alloc((size_t)200064 * 256 * 2);   // L0/L1: fp8 view; L2: bf16 view
    bf16*  h1b   = (bf16*)alloc((size_t)50048 * 256 * 2);
    bf16*  h2b   = (bf16*)alloc((size_t)10112 * 256 * 2);
    bf16*  xsb   = (bf16*)alloc((size_t)50048 * 256 * 2);    // skip-GEMM output (xs)
    float* elb   = (float*)alloc((size_t)200064 * 4 * 4);
    float* erb   = (float*)alloc((size_t)50048 * 4 * 4);
    bf16* Wt[3]; bf16* Wst[2];
    Wt[0]  = (bf16*)alloc(256 * 128 * 2);
    Wt[1]  = (bf16*)alloc(256 * 256 * 2);
    Wt[2]  = (bf16*)alloc(256 * 256 * 2);
    Wst[0] = (bf16*)alloc(256 * 128 * 2);
    Wst[1] = (bf16*)alloc(256 * 256 * 2);
    int* offs_all  = (int*)alloc(62051 * 4);
    int* ssrc_all  = (int*)alloc(1300000 * 4);
    int* stage_all = (int*)alloc(1300000 * 4);
    int* blockhist = (int*)alloc(3 * NBIN * NBLK * 4);
    int* binbase   = (int*)alloc(3 * NBIN * NBLK * 4);
    int* bbase     = (int*)alloc(3 * (NBIN + 1) * 4);

    unsigned char* fsb8 = (unsigned char*)fsb;

    const int OOFF[3] = {0, 50001, 60002};
    const int SOFF[3] = {0, 800000, 1200000};

    // weights transpose-cast + per-layer coarse histograms in one dispatch
    precast_all<<<dim3(128, 8), 256, 0, stream>>>(W[0], W[1], W[2], Ws[0], Ws[1],
                                                  Wt[0], Wt[1], Wt[2], Wst[0], Wst[1],
                                                  dstp[0], dstp[1], dstp[2], blockhist);

    coarse_scan<<<3, NBIN, 0, stream>>>(blockhist, bbase, offs_all);
    bin_scan<<<dim3(NBIN, 3), NBLK, 0, stream>>>(blockhist, bbase, binbase);
    bin_scatter<<<dim3(NBLK, 3), 256, 0, stream>>>(srcp[0], dstp[0], srcp[1], dstp[1],
                                                   srcp[2], dstp[2], binbase, stage_all);
    bin_expand<<<dim3(NBIN, 3), 256, 0, stream>>>(stage_all, bbase, offs_all, ssrc_all);

    // ---- layer 0 (D=64, cin=128): BIG shape (1563 blocks); attn fuses h1 ----
    gemm_mfma<1, 0, 1, 1, 1, 1, 0><<<dim3(1, 1563), 512, 0, stream>>>(
        x, Wt[0], nullptr, nullptr, al[0], ar[0], elb, erb, fsb8, 200000, 256, 128, 50000,
        Wst[0], xsb);
    attn_agg64<1><<<12500, 256, 0, stream>>>(fsb8, elb, erb, bb[0], offs_all + OOFF[0],
                                             ssrc_all + SOFF[0], xsb, bs[0], h1b, 50000);

    // ---- layer 1 (D=64, cin=256): SMALL shape (782 blocks); attn fuses h2 ----
    gemm_mfma<0, 0, 1, 1, 0, 1, 0><<<dim3(1, 782), 256, 0, stream>>>(
        h1b, Wt[1], nullptr, nullptr, al[1], ar[1], elb, erb, fsb8, 50000, 256, 256, 10000,
        Wst[1], xsb);
    attn_agg64<1><<<2500, 256, 0, stream>>>(fsb8, elb, erb, bb[1], offs_all + OOFF[1],
                                            ssrc_all + SOFF[1], xsb, bs[1], h2b, 10000);

    // ---- layer 2 (D=47, cin=256): SMALL shape (157 blocks); GEMM fuses el/er (EL2) ----
    gemm_mfma<0, 0, 0, 0, 0, 0, 1><<<dim3(1, 157), 256, 0, stream>>>(
        h2b, Wt[2], nullptr, nullptr, al[2], ar[2], elb, erb, fsb, 10000, 188, 256, 2048,
        nullptr, nullptr);
    attn_final_gen<<<512, 256, 0, stream>>>(fsb, elb, erb, bb[2], offs_all + OOFF[2], ssrc_all + SOFF[2],
                                            h2b, Ws[2], bs[2], (float*)d_out, 47, 2048);
}